// Round 2
// baseline (1936.410 us; speedup 1.0000x reference)
//
#include <hip/hip_runtime.h>
#include <cstdint>
#include <cstddef>

typedef unsigned short u16;
typedef float f32x4 __attribute__((ext_vector_type(4)));
typedef __bf16 bf16x8 __attribute__((ext_vector_type(8)));

#define B_DIM   8192
#define IN_DIM  1024
#define HID_DIM 4096
#define OUT_DIM 1024
#define NEXP    8

// ---------- helpers ----------
__device__ __forceinline__ u16 f2b(float f) {
    uint32_t u = __builtin_bit_cast(uint32_t, f);
    u += 0x7fffu + ((u >> 16) & 1u);      // RNE
    return (u16)(u >> 16);
}
__device__ __forceinline__ float b2f(u16 b) {
    uint32_t u = ((uint32_t)b) << 16;
    return __builtin_bit_cast(float, u);
}
// tanh-form GELU via one v_exp_f32: gelu(x) = x * e/(e+1), e = exp(2*y).
__device__ __forceinline__ float gelu_fast(float x) {
    float y = x * (0.7978845608f + 0.03567740814f * x * x);
    float a = fminf(y * 2.8853900818f, 80.0f);     // 2*log2(e)*y, clamp overflow
    float e = __builtin_amdgcn_exp2f(a);
    return x * e * __builtin_amdgcn_rcpf(e + 1.0f);
}
__device__ __forceinline__ void async_cp16(const void* g, void* l) {
    __builtin_amdgcn_global_load_lds(
        (const __attribute__((address_space(1))) void*)g,
        (__attribute__((address_space(3))) void*)l,
        16, 0, 0);
}

// ---------- fp32 -> bf16 convert ----------
__global__ __launch_bounds__(256)
void cvt_bf16(const float* __restrict__ in, u16* __restrict__ out, int n4) {
    int i = blockIdx.x * 256 + threadIdx.x;
    if (i >= n4) return;
    float4 v = *(const float4*)&in[(size_t)i * 4];
    uint2 o;
    o.x = (uint32_t)f2b(v.x) | ((uint32_t)f2b(v.y) << 16);
    o.y = (uint32_t)f2b(v.z) | ((uint32_t)f2b(v.w) << 16);
    *(uint2*)&out[(size_t)i * 4] = o;
}

// ---------- transpose both expert weights: [K,N] fp32 -> [N,K] bf16 ----------
__global__ __launch_bounds__(256)
void transpose_cvt2(const float* __restrict__ W1e, u16* __restrict__ w1t,
                    const float* __restrict__ W2e, u16* __restrict__ w2t) {
    __shared__ float tile[32][33];
    const float* W; u16* Wt; int K, N, n0, k0;
    if (blockIdx.z == 0) {
        W = W1e; Wt = w1t; K = IN_DIM; N = HID_DIM;
        n0 = blockIdx.x * 32; k0 = blockIdx.y * 32;
    } else {
        W = W2e; Wt = w2t; K = HID_DIM; N = OUT_DIM;
        n0 = blockIdx.y * 32; k0 = blockIdx.x * 32;
    }
    const int tx = threadIdx.x & 31, ty = threadIdx.x >> 5;   // ty 0..7
#pragma unroll
    for (int i = 0; i < 4; ++i) {
        int k = k0 + ty + i * 8;
        tile[ty + i * 8][tx] = W[(size_t)k * N + n0 + tx];
    }
    __syncthreads();
#pragma unroll
    for (int i = 0; i < 4; ++i) {
        int n = n0 + ty + i * 8;
        Wt[(size_t)n * K + k0 + tx] = f2b(tile[tx][ty + i * 8]);
    }
}

// ---------- 256x256 bf16 GEMM, register-pipelined counted-vmcnt loop ----------
// C = A[M,K(lda)] * Bt[N,K(ldb)]^T (+bias, bf16 out) or fp32 partial out
// (split-K via blockIdx.z, slice depth Ksl).
// 512 thr = 8 waves (2M x 4N), per-wave 128x64 (acc[8][4]). BK=32.
// Overlap mechanism: in-wave register double-buffer — iter t issues
// {stage tile t+3 (4 gloads), ds_read tile t+1's 12 frags into the OTHER
// named set}, then 32 MFMA on tile t's set. Data dependence (not barriers)
// orders reads vs MFMA; the compiler interleaves them (LDS pipe || matrix
// pipe). One asm s_barrier per iter (compiler-fenced via "memory" —
// __builtin s_barrier is IntrNoMem and does NOT fence, R1 lesson).
// Counted vmcnt(4) before the barrier: drains through tile t+2, leaves
// t+3 in flight -> loads never fully drain in steady state.
// Ring lifecycle: stage slot (t+3)&3 == (t-1)&3; tile t-1's reads were
// lgkm-completed before iter t-1's MFMA cluster, and the barrier at end of
// iter t-1 publishes that to all waves. Requires NT=Ksl/32 even, >=4.
template<int F32OUT>
__global__ __launch_bounds__(512, 2)
void gemm256_pipe(const u16* __restrict__ A, const u16* __restrict__ Bt,
                  const float* __restrict__ bias, void* __restrict__ Cv,
                  int M, int N, int lda, int ldb, int Ksl) {
    __shared__ __attribute__((aligned(16))) u16 sA[4][256 * 32];
    __shared__ __attribute__((aligned(16))) u16 sB[4][256 * 32];

    const int tid  = threadIdx.x;
    const int wid  = tid >> 6;
    const int lane = tid & 63;
    const int quad = lane >> 4;
    const int lr   = lane & 15;
    const int wm   = wid >> 2;        // 0..1
    const int wn   = wid & 3;         // 0..3
    const int z    = blockIdx.z;      // K-slice (split-K); 0 otherwise

    // XCD-aware supertile swizzle (per-slice; NY multiple of 8).
    const int NX = gridDim.x, NY = gridDim.y;
    const int bid = blockIdx.y * NX + blockIdx.x;
    const int xcd = bid & 7;
    const int j   = bid >> 3;
    const int yl  = j / NX;
    const int bx  = j - yl * NX;
    const int by  = xcd * (NY >> 3) + yl;

    const int m0 = by * 256;
    const int n0 = bx * 256;

    const int sr  = lane >> 2;                                 // 0..15 row-in-group
    const int scl = ((lane & 3) ^ ((lane >> 3) & 3)) * 8;      // pre-swizzled src chunk
    const int qsw = (lr >> 1) & 3;                             // read-side XOR

    // staging pointers (per-lane global, wave-uniform-base LDS dest)
    const u16* Ag0 = A  + ((size_t)z * Ksl) + ((size_t)m0 + wid * 16 + sr) * (size_t)lda + scl;
    const u16* Ag1 = Ag0 + (size_t)128 * lda;
    const u16* Bg0 = Bt + ((size_t)z * Ksl) + ((size_t)n0 + wid * 16 + sr) * (size_t)ldb + scl;
    const u16* Bg1 = Bg0 + (size_t)128 * ldb;

    // LDS read bases (element idx); mi/ni add compile-time mi*512 / ni*512
    const int rdA = (wm * 128 + lr) * 32 + ((quad ^ qsw) * 8);
    const int rdB = (wn * 64  + lr) * 32 + ((quad ^ qsw) * 8);

    const int NT = Ksl >> 5;          // K-tiles of 32 (even, >=4)

#define STAGE(tt) do {                                                        \
        const int sl_ = (tt) & 3;                                             \
        const size_t ko_ = (size_t)(tt) * 32;                                 \
        async_cp16(Ag0 + ko_, &sA[sl_][wid * 512]);                           \
        async_cp16(Ag1 + ko_, &sA[sl_][4096 + wid * 512]);                    \
        async_cp16(Bg0 + ko_, &sB[sl_][wid * 512]);                           \
        async_cp16(Bg1 + ko_, &sB[sl_][4096 + wid * 512]);                    \
    } while (0)

#define READF(afd, bfd, tt) do {                                              \
        const u16* sa_ = &sA[(tt) & 3][0];                                    \
        const u16* sb_ = &sB[(tt) & 3][0];                                    \
        _Pragma("unroll")                                                     \
        for (int mi = 0; mi < 8; ++mi)                                        \
            afd[mi] = *(const bf16x8*)&sa_[rdA + mi * 512];                   \
        _Pragma("unroll")                                                     \
        for (int ni = 0; ni < 4; ++ni)                                        \
            bfd[ni] = *(const bf16x8*)&sb_[rdB + ni * 512];                   \
    } while (0)

#define CLUSTER(afc, bfc) do {                                                \
        __builtin_amdgcn_s_setprio(1);                                        \
        _Pragma("unroll")                                                     \
        for (int mi = 0; mi < 8; ++mi)                                        \
            _Pragma("unroll")                                                 \
            for (int ni = 0; ni < 4; ++ni)                                    \
                acc[mi][ni] = __builtin_amdgcn_mfma_f32_16x16x32_bf16(        \
                    afc[mi], bfc[ni], acc[mi][ni], 0, 0, 0);                  \
        __builtin_amdgcn_s_setprio(0);                                        \
    } while (0)

#define BODY(tt, afc, bfc, afn, bfn) do {                                     \
        const int pre_ = (tt) + 3;                                            \
        if (pre_ < NT) STAGE(pre_);                                           \
        READF(afn, bfn, (tt) + 1);                                            \
        CLUSTER(afc, bfc);                                                    \
        if (pre_ < NT) asm volatile("s_waitcnt vmcnt(4)" ::: "memory");       \
        else           asm volatile("s_waitcnt vmcnt(0)" ::: "memory");       \
        asm volatile("s_barrier" ::: "memory");                               \
    } while (0)

    // prologue: stage tiles 0..2; ensure tiles 0,1 resident; read tile 0 frags
    STAGE(0); STAGE(1); STAGE(2);
    asm volatile("s_waitcnt vmcnt(4)" ::: "memory");
    asm volatile("s_barrier" ::: "memory");

    bf16x8 afA[8], bfA[4], afB[8], bfB[4];
    READF(afA, bfA, 0);

    f32x4 acc[8][4] = {};

    // pipelined iters t = 0..NT-2 (NT even): pairs keep frag-set parity static
#pragma unroll 1
    for (int t = 0; t < NT - 2; t += 2) {
        BODY(t,     afA, bfA, afB, bfB);
        BODY(t + 1, afB, bfB, afA, bfA);
    }
    BODY(NT - 2, afA, bfA, afB, bfB);
    CLUSTER(afB, bfB);                     // tile NT-1, no further staging

#undef BODY
#undef CLUSTER
#undef READF
#undef STAGE

    // epilogue: D col = lane&15, row = quad*4 + reg
    if constexpr (F32OUT) {
        float* C = (float*)Cv + (size_t)z * ((size_t)M * N);
#pragma unroll
        for (int mi = 0; mi < 8; ++mi) {
            const int mr = m0 + wm * 128 + mi * 16 + quad * 4;
#pragma unroll
            for (int r = 0; r < 4; ++r) {
                float* Crow = C + (size_t)(mr + r) * N + n0 + wn * 64 + lr;
#pragma unroll
                for (int ni = 0; ni < 4; ++ni)
                    Crow[ni * 16] = acc[mi][ni][r];
            }
        }
    } else {
        u16* C = (u16*)Cv;
        float bvv[4];
#pragma unroll
        for (int ni = 0; ni < 4; ++ni)
            bvv[ni] = bias[n0 + wn * 64 + ni * 16 + lr];
#pragma unroll
        for (int mi = 0; mi < 8; ++mi) {
            const int mr = m0 + wm * 128 + mi * 16 + quad * 4;
#pragma unroll
            for (int r = 0; r < 4; ++r) {
                u16* Crow = C + (size_t)(mr + r) * N + n0 + wn * 64 + lr;
#pragma unroll
                for (int ni = 0; ni < 4; ++ni)
                    Crow[ni * 16] = f2b(acc[mi][ni][r] + bvv[ni]);
            }
        }
    }
}

// ---------- bf16 GEMM 128x128 (fallback for GEMM2 if ws too small) ----------
__global__ __launch_bounds__(256)
void gemm_bt_bias(const u16* __restrict__ A, const u16* __restrict__ Bt,
                  const float* __restrict__ bias, u16* __restrict__ C,
                  int M, int N, int K) {
    __shared__ __attribute__((aligned(16))) u16 sA[2][128 * 32];
    __shared__ __attribute__((aligned(16))) u16 sB[2][128 * 32];

    const int tid  = threadIdx.x;
    const int wid  = tid >> 6;
    const int lane = tid & 63;
    const int quad = lane >> 4;
    const int lr   = lane & 15;
    const int wm   = wid & 1;
    const int wn   = wid >> 1;

    const int NX = gridDim.x, NY = gridDim.y;
    const int bid = blockIdx.y * NX + blockIdx.x;
    const int xcd = bid & 7;
    const int j   = bid >> 3;
    const int yl  = j / NX;
    const int bx  = j - yl * NX;
    const int by  = xcd * (NY >> 3) + yl;

    const int m0 = by * 128;
    const int n0 = bx * 128;

    const int sr  = lane >> 2;
    const int scl = ((lane & 3) ^ ((lane >> 3) & 3)) * 8;
    const int qsw = (lr >> 1) & 3;

    const u16* Ag = A + (size_t)m0 * K;
    const u16* Bg = Bt + (size_t)n0 * K;

    f32x4 acc[4][4] = {};

    for (int k0 = 0; k0 < K; k0 += 64) {
#pragma unroll
        for (int s = 0; s < 2; ++s) {
#pragma unroll
            for (int i = 0; i < 2; ++i) {
                const int rb = wid * 32 + i * 16;
                async_cp16(Ag + (size_t)(rb + sr) * K + k0 + s * 32 + scl,
                           &sA[s][rb * 32]);
                async_cp16(Bg + (size_t)(rb + sr) * K + k0 + s * 32 + scl,
                           &sB[s][rb * 32]);
            }
        }
        __syncthreads();

#pragma unroll
        for (int s = 0; s < 2; ++s) {
            bf16x8 af[4], bfr[4];
#pragma unroll
            for (int mi = 0; mi < 4; ++mi)
                af[mi] = *(const bf16x8*)
                    &sA[s][(wm * 64 + mi * 16 + lr) * 32 + ((quad ^ qsw) * 8)];
#pragma unroll
            for (int ni = 0; ni < 4; ++ni)
                bfr[ni] = *(const bf16x8*)
                    &sB[s][(wn * 64 + ni * 16 + lr) * 32 + ((quad ^ qsw) * 8)];

#pragma unroll
            for (int mi = 0; mi < 4; ++mi)
#pragma unroll
                for (int ni = 0; ni < 4; ++ni)
                    acc[mi][ni] = __builtin_amdgcn_mfma_f32_16x16x32_bf16(
                        af[mi], bfr[ni], acc[mi][ni], 0, 0, 0);
        }

        __syncthreads();
    }

    float bvv[4];
#pragma unroll
    for (int ni = 0; ni < 4; ++ni)
        bvv[ni] = bias[n0 + wn * 64 + ni * 16 + lr];

#pragma unroll
    for (int mi = 0; mi < 4; ++mi) {
        const int mr = m0 + wm * 64 + mi * 16 + quad * 4;
#pragma unroll
        for (int r = 0; r < 4; ++r) {
            u16* Crow = C + (size_t)(mr + r) * N + n0 + wn * 64 + lr;
#pragma unroll
            for (int ni = 0; ni < 4; ++ni)
                Crow[ni * 16] = f2b(acc[mi][ni][r] + bvv[ni]);
        }
    }
}

// ---------- fused LN(4096) + GELU, in-place on bf16 h ----------
__global__ __launch_bounds__(256)
void ln_gelu_hid(u16* __restrict__ h, const float* __restrict__ g,
                 const float* __restrict__ be) {
    __shared__ float red[8];
    const int row = blockIdx.x;
    u16* hp = h + (size_t)row * HID_DIM;
    const int t = threadIdx.x;

    uint4 v0 = *(const uint4*)&hp[t * 8];
    uint4 v1 = *(const uint4*)&hp[(t + 256) * 8];

    float vals[16];
    {
        const uint32_t w0[4] = {v0.x, v0.y, v0.z, v0.w};
        const uint32_t w1[4] = {v1.x, v1.y, v1.z, v1.w};
#pragma unroll
        for (int q = 0; q < 4; ++q) {
            vals[q * 2]     = b2f((u16)(w0[q] & 0xffffu));
            vals[q * 2 + 1] = b2f((u16)(w0[q] >> 16));
            vals[8 + q * 2]     = b2f((u16)(w1[q] & 0xffffu));
            vals[8 + q * 2 + 1] = b2f((u16)(w1[q] >> 16));
        }
    }
    float s = 0.f, ss = 0.f;
#pragma unroll
    for (int i = 0; i < 16; ++i) { s += vals[i]; ss += vals[i] * vals[i]; }

    float4 gv[4], bv[4];
    gv[0] = *(const float4*)&g[t * 8];
    gv[1] = *(const float4*)&g[t * 8 + 4];
    gv[2] = *(const float4*)&g[(t + 256) * 8];
    gv[3] = *(const float4*)&g[(t + 256) * 8 + 4];
    bv[0] = *(const float4*)&be[t * 8];
    bv[1] = *(const float4*)&be[t * 8 + 4];
    bv[2] = *(const float4*)&be[(t + 256) * 8];
    bv[3] = *(const float4*)&be[(t + 256) * 8 + 4];

#pragma unroll
    for (int off = 32; off > 0; off >>= 1) {
        s += __shfl_down(s, off, 64);
        ss += __shfl_down(ss, off, 64);
    }
    if ((t & 63) == 0) { red[(t >> 6) * 2] = s; red[(t >> 6) * 2 + 1] = ss; }
    __syncthreads();
    s  = red[0] + red[2] + red[4] + red[6];
    ss = red[1] + red[3] + red[5] + red[7];
    const float mean = s * (1.f / HID_DIM);
    const float rstd = rsqrtf(ss * (1.f / HID_DIM) - mean * mean + 1e-5f);

    const float* gf = (const float*)gv;
    const float* bf = (const float*)bv;
#pragma unroll
    for (int j = 0; j < 2; ++j) {
        uint4 o;
        uint32_t* ow = (uint32_t*)&o;
#pragma unroll
        for (int q = 0; q < 4; ++q) {
            const int k = j * 8 + q * 2;
            float u0 = gelu_fast((vals[k]     - mean) * rstd * gf[k]     + bf[k]);
            float u1 = gelu_fast((vals[k + 1] - mean) * rstd * gf[k + 1] + bf[k + 1]);
            ow[q] = (uint32_t)f2b(u0) | ((uint32_t)f2b(u1) << 16);
        }
        *(uint4*)&hp[(t + j * 256) * 8] = o;
    }
}

// ---------- fused LN(1024) + GELU + weighted accumulate (bf16 y path) ----------
__global__ __launch_bounds__(256)
void ln_gelu_combine(const u16* __restrict__ y, const float* __restrict__ g,
                     const float* __restrict__ be, const float* __restrict__ wts,
                     float* __restrict__ out, int e, int first) {
    __shared__ float red[8];
    const int row = blockIdx.x;
    const u16* yp = y + (size_t)row * OUT_DIM;
    const int t = threadIdx.x;

    uint2 v = *(const uint2*)&yp[t * 4];
    float f0 = b2f((u16)(v.x & 0xffffu)), f1 = b2f((u16)(v.x >> 16));
    float f2 = b2f((u16)(v.y & 0xffffu)), f3 = b2f((u16)(v.y >> 16));
    float s = f0 + f1 + f2 + f3;
    float ss = f0 * f0 + f1 * f1 + f2 * f2 + f3 * f3;

    const int n = t * 4;
    float4 gv = *(const float4*)&g[n];
    float4 bvv = *(const float4*)&be[n];

#pragma unroll
    for (int off = 32; off > 0; off >>= 1) {
        s += __shfl_down(s, off, 64);
        ss += __shfl_down(ss, off, 64);
    }
    if ((t & 63) == 0) { red[(t >> 6) * 2] = s; red[(t >> 6) * 2 + 1] = ss; }
    __syncthreads();
    s  = red[0] + red[2] + red[4] + red[6];
    ss = red[1] + red[3] + red[5] + red[7];
    const float mean = s * (1.f / OUT_DIM);
    const float rstd = rsqrtf(ss * (1.f / OUT_DIM) - mean * mean + 1e-5f);

    const float w = wts[(size_t)row * NEXP + e];
    float4 o;
    if (first) { o.x = o.y = o.z = o.w = 0.f; }
    else       { o = *(const float4*)&out[(size_t)row * OUT_DIM + n]; }
    o.x += w * gelu_fast((f0 - mean) * rstd * gv.x + bvv.x);
    o.y += w * gelu_fast((f1 - mean) * rstd * gv.y + bvv.y);
    o.z += w * gelu_fast((f2 - mean) * rstd * gv.z + bvv.z);
    o.w += w * gelu_fast((f3 - mean) * rstd * gv.w + bvv.w);
    *(float4*)&out[(size_t)row * OUT_DIM + n] = o;
}

// ---------- split-K combine: y = p0+p1+b2, then LN + GELU + weighted acc ----------
__global__ __launch_bounds__(256)
void ln_gelu_combine_f32(const float* __restrict__ P, const float* __restrict__ g,
                         const float* __restrict__ be, const float* __restrict__ bs,
                         const float* __restrict__ wts, float* __restrict__ out,
                         int e, int first) {
    __shared__ float red[8];
    const int row = blockIdx.x;
    const int t = threadIdx.x;
    const int n = t * 4;

    const float* p0 = P + (size_t)row * OUT_DIM + n;
    const float* p1 = p0 + (size_t)B_DIM * OUT_DIM;
    float4 a  = *(const float4*)p0;
    float4 b  = *(const float4*)p1;
    float4 c  = *(const float4*)&bs[n];
    float f0 = a.x + b.x + c.x, f1 = a.y + b.y + c.y;
    float f2 = a.z + b.z + c.z, f3 = a.w + b.w + c.w;
    float s = f0 + f1 + f2 + f3;
    float ss = f0 * f0 + f1 * f1 + f2 * f2 + f3 * f3;

    float4 gv = *(const float4*)&g[n];
    float4 bvv = *(const float4*)&be[n];

#pragma unroll
    for (int off = 32; off > 0; off >>= 1) {
        s += __shfl_down(s, off, 64);
        ss += __shfl_down(ss, off, 64);
    }
    if ((t & 63) == 0) { red[(t >> 6) * 2] = s; red[(t >> 6) * 2 + 1] = ss; }
    __syncthreads();
    s  = red[0] + red[2] + red[4] + red[6];
    ss = red[1] + red[3] + red[5] + red[7];
    const float mean = s * (1.f / OUT_DIM);
    const float rstd = rsqrtf(ss * (1.f / OUT_DIM) - mean * mean + 1e-5f);

    const float w = wts[(size_t)row * NEXP + e];
    float4 o;
    if (first) { o.x = o.y = o.z = o.w = 0.f; }
    else       { o = *(const float4*)&out[(size_t)row * OUT_DIM + n]; }
    o.x += w * gelu_fast((f0 - mean) * rstd * gv.x + bvv.x);
    o.y += w * gelu_fast((f1 - mean) * rstd * gv.y + bvv.y);
    o.z += w * gelu_fast((f2 - mean) * rstd * gv.z + bvv.z);
    o.w += w * gelu_fast((f3 - mean) * rstd * gv.w + bvv.w);
    *(float4*)&out[(size_t)row * OUT_DIM + n] = o;
}

// ---------- launch ----------
extern "C" void kernel_launch(void* const* d_in, const int* in_sizes, int n_in,
                              void* d_out, int out_size, void* d_ws, size_t ws_size,
                              hipStream_t stream) {
    (void)in_sizes; (void)n_in; (void)out_size;
    const float* x   = (const float*)d_in[0];  // [8192,1024]
    const float* wts = (const float*)d_in[1];  // [8192,8]
    const float* W1  = (const float*)d_in[2];  // [8,1024,4096]
    const float* b1  = (const float*)d_in[3];  // [8,4096]
    const float* g1  = (const float*)d_in[4];  // [8,4096]
    const float* be1 = (const float*)d_in[5];  // [8,4096]
    const float* W2  = (const float*)d_in[6];  // [8,4096,1024]
    const float* b2  = (const float*)d_in[7];  // [8,1024]
    const float* g2  = (const float*)d_in[8];  // [8,1024]
    const float* be2 = (const float*)d_in[9];  // [8,1024]
    float* out = (float*)d_out;                // [8192,1024]

    // workspace carve: xb 16MB | w1t 8MB | w2t 8MB | h 64MB | P 64MB (or y 16MB)
    char* p = (char*)d_ws;
    u16* xb  = (u16*)p; p += (size_t)B_DIM * IN_DIM * 2;
    u16* w1t = (u16*)p; p += (size_t)HID_DIM * IN_DIM * 2;
    u16* w2t = (u16*)p; p += (size_t)OUT_DIM * HID_DIM * 2;
    u16* h   = (u16*)p; p += (size_t)B_DIM * HID_DIM * 2;
    float* P = (float*)p;                      // split path: 2 x 32MB fp32 partials
    u16*  y  = (u16*)p;                        // fallback path: 16MB bf16

    const size_t need = (size_t)B_DIM * IN_DIM * 2 + (size_t)HID_DIM * IN_DIM * 2 +
                        (size_t)OUT_DIM * HID_DIM * 2 + (size_t)B_DIM * HID_DIM * 2 +
                        (size_t)2 * B_DIM * OUT_DIM * 4;   // 160 MB
    const int splitk = (ws_size >= need) ? 1 : 0;

    cvt_bf16<<<(B_DIM * IN_DIM / 4 + 255) / 256, 256, 0, stream>>>(x, xb, B_DIM * IN_DIM / 4);

    for (int e = 0; e < NEXP; ++e) {
        transpose_cvt2<<<dim3(HID_DIM / 32, IN_DIM / 32, 2), 256, 0, stream>>>(
            W1 + (size_t)e * IN_DIM * HID_DIM, w1t,
            W2 + (size_t)e * HID_DIM * OUT_DIM, w2t);
        // h = xb @ W1[e] + b1[e]   (M=8192, N=4096, K=1024)
        gemm256_pipe<0><<<dim3(HID_DIM / 256, B_DIM / 256, 1), 512, 0, stream>>>(
            xb, w1t, b1 + (size_t)e * HID_DIM, h, B_DIM, HID_DIM, IN_DIM, IN_DIM, IN_DIM);
        // h = gelu(ln(h))
        ln_gelu_hid<<<B_DIM, 256, 0, stream>>>(h, g1 + (size_t)e * HID_DIM,
                                               be1 + (size_t)e * HID_DIM);
        if (splitk) {
            // P[s] = h @ W2[e] (K-slice s of 2048), fp32 partials; 256 blocks = 1/CU
            gemm256_pipe<1><<<dim3(OUT_DIM / 256, B_DIM / 256, 2), 512, 0, stream>>>(
                h, w2t, nullptr, P, B_DIM, OUT_DIM, HID_DIM, HID_DIM, HID_DIM / 2);
            // out (+)= wts[:,e] * gelu(ln(p0+p1+b2))
            ln_gelu_combine_f32<<<B_DIM, 256, 0, stream>>>(
                P, g2 + (size_t)e * OUT_DIM, be2 + (size_t)e * OUT_DIM,
                b2 + (size_t)e * OUT_DIM, wts, out, e, e == 0 ? 1 : 0);
        } else {
            // fallback: 128^2 GEMM2 + bf16 combine
            gemm_bt_bias<<<dim3(OUT_DIM / 128, B_DIM / 128), 256, 0, stream>>>(
                h, w2t, b2 + (size_t)e * OUT_DIM, y, B_DIM, OUT_DIM, HID_DIM);
            ln_gelu_combine<<<B_DIM, 256, 0, stream>>>(y, g2 + (size_t)e * OUT_DIM,
                                                       be2 + (size_t)e * OUT_DIM, wts, out,
                                                       e, e == 0 ? 1 : 0);
        }
    }
}

// Round 3
// 1861.693 us; speedup vs baseline: 1.0401x; 1.0401x over previous
//
#include <hip/hip_runtime.h>
#include <cstdint>
#include <cstddef>

typedef unsigned short u16;
typedef float f32x4 __attribute__((ext_vector_type(4)));
typedef __bf16 bf16x8 __attribute__((ext_vector_type(8)));

#define B_DIM   8192
#define IN_DIM  1024
#define HID_DIM 4096
#define OUT_DIM 1024
#define NEXP    8

// ---------- helpers ----------
__device__ __forceinline__ u16 f2b(float f) {
    uint32_t u = __builtin_bit_cast(uint32_t, f);
    u += 0x7fffu + ((u >> 16) & 1u);      // RNE
    return (u16)(u >> 16);
}
__device__ __forceinline__ float b2f(u16 b) {
    uint32_t u = ((uint32_t)b) << 16;
    return __builtin_bit_cast(float, u);
}
// tanh-form GELU via one v_exp_f32: gelu(x) = x * e/(e+1), e = exp(2*y).
__device__ __forceinline__ float gelu_fast(float x) {
    float y = x * (0.7978845608f + 0.03567740814f * x * x);
    float a = fminf(y * 2.8853900818f, 80.0f);     // 2*log2(e)*y, clamp overflow
    float e = __builtin_amdgcn_exp2f(a);
    return x * e * __builtin_amdgcn_rcpf(e + 1.0f);
}
__device__ __forceinline__ void async_cp16(const void* g, void* l) {
    __builtin_amdgcn_global_load_lds(
        (const __attribute__((address_space(1))) void*)g,
        (__attribute__((address_space(3))) void*)l,
        16, 0, 0);
}

// ---------- fp32 -> bf16 convert ----------
__global__ __launch_bounds__(256)
void cvt_bf16(const float* __restrict__ in, u16* __restrict__ out, int n4) {
    int i = blockIdx.x * 256 + threadIdx.x;
    if (i >= n4) return;
    float4 v = *(const float4*)&in[(size_t)i * 4];
    uint2 o;
    o.x = (uint32_t)f2b(v.x) | ((uint32_t)f2b(v.y) << 16);
    o.y = (uint32_t)f2b(v.z) | ((uint32_t)f2b(v.w) << 16);
    *(uint2*)&out[(size_t)i * 4] = o;
}

// ---------- transpose both expert weights: [K,N] fp32 -> [N,K] bf16 ----------
__global__ __launch_bounds__(256)
void transpose_cvt2(const float* __restrict__ W1e, u16* __restrict__ w1t,
                    const float* __restrict__ W2e, u16* __restrict__ w2t) {
    __shared__ float tile[32][33];
    const float* W; u16* Wt; int K, N, n0, k0;
    if (blockIdx.z == 0) {
        W = W1e; Wt = w1t; K = IN_DIM; N = HID_DIM;
        n0 = blockIdx.x * 32; k0 = blockIdx.y * 32;
    } else {
        W = W2e; Wt = w2t; K = HID_DIM; N = OUT_DIM;
        n0 = blockIdx.y * 32; k0 = blockIdx.x * 32;
    }
    const int tx = threadIdx.x & 31, ty = threadIdx.x >> 5;   // ty 0..7
#pragma unroll
    for (int i = 0; i < 4; ++i) {
        int k = k0 + ty + i * 8;
        tile[ty + i * 8][tx] = W[(size_t)k * N + n0 + tx];
    }
    __syncthreads();
#pragma unroll
    for (int i = 0; i < 4; ++i) {
        int n = n0 + ty + i * 8;
        Wt[(size_t)n * K + k0 + tx] = f2b(tile[tx][ty + i * 8]);
    }
}

// ---------- 256x256 bf16 GEMM, m201-style 8-phase schedule ----------
// C = A[M,K(lda)] * Bt[N,K(ldb)]^T (+bias, bf16 out) or fp32 partial out
// (split-K via blockIdx.z, slice depth Ksl). 512 thr = 8 waves (2M x 4N),
// per-wave 128x64 (acc[8][4]). BK=64, staged as two k-halves of 256x32.
// Per K-tile: 4 phases, each { 4-8 ds_read_b128 || stage 1 k-half
// (2 global_load_lds) -> s_barrier -> lgkmcnt(0) -> sched_barrier(0)
// -> setprio(1) -> 16 MFMA -> setprio(0) -> s_barrier }.
// Counted vmcnt(4) ONLY at phases 2 and 4 (2 loads x 2 k-halves in
// flight; each wait publishes the k-half that was staged 3-4 phases
// earlier). 2-buffer LDS (128 KiB). Last tile peeled with exact drains.
// Swizzle: stage source chunk lc = (pc ^ ((row>>1)&3)); read chunk
// (quad ^ ((lr>>1)&3)) — same involution both sides, conflict-free
// (0 measured through R2). Requires NT=Ksl/64 >= 2, N%256==0, M%256==0,
// gridDim.y % 8 == 0.
template<int F32OUT>
__global__ __launch_bounds__(512, 2)
void gemm256_8ph(const u16* __restrict__ A, const u16* __restrict__ Bt,
                 const float* __restrict__ bias, void* __restrict__ Cv,
                 int M, int N, int lda, int ldb, int Ksl) {
    __shared__ __attribute__((aligned(16))) u16 sA[32768];  // [2 buf][2 kh][256*32]
    __shared__ __attribute__((aligned(16))) u16 sB[32768];

    const int tid  = threadIdx.x;
    const int wid  = tid >> 6;
    const int lane = tid & 63;
    const int quad = lane >> 4;
    const int lr   = lane & 15;
    const int wm   = wid >> 2;        // 0..1
    const int wn   = wid & 3;         // 0..3
    const int z    = blockIdx.z;      // K-slice (split-K); 0 otherwise

    // XCD-aware supertile swizzle (NY multiple of 8).
    const int NX = gridDim.x, NY = gridDim.y;
    const int bid = blockIdx.y * NX + blockIdx.x;
    const int xcd = bid & 7;
    const int j   = bid >> 3;
    const int yl  = j / NX;
    const int bx  = j - yl * NX;
    const int by  = xcd * (NY >> 3) + yl;
    const int m0 = by * 256;
    const int n0 = bx * 256;

    const int qsw   = (lr >> 1) & 3;                       // read-side XOR
    const int row_s = tid >> 2;                            // 0..127 staging row
    const int lc    = ((tid & 3) ^ ((tid >> 3) & 3)) * 8;  // pre-swizzled src chunk

    const u16* Ast = A  + (size_t)z * Ksl + (size_t)(m0 + row_s) * lda + lc;
    const u16* Bst = Bt + (size_t)z * Ksl + (size_t)(n0 + row_s) * ldb + lc;

    const int rdA = (wm * 128 + lr) * 32 + ((quad ^ qsw) * 8);
    const int rdB = (wn * 64  + lr) * 32 + ((quad ^ qsw) * 8);
    const int d0  = tid * 8;          // u16 idx of load-0 dest within a k-half

    const int NT = Ksl >> 6;          // BK=64 tiles (>= 2)

    f32x4 acc[8][4] = {};
    bf16x8 av[4], bv[4];

#define STG_A(hb, ko) do {                                                     \
        async_cp16(Ast + (ko),                      &sA[(hb) + d0]);           \
        async_cp16(Ast + (ko) + (size_t)128 * lda,  &sA[(hb) + d0 + 4096]);    \
    } while (0)
#define STG_B(hb, ko) do {                                                     \
        async_cp16(Bst + (ko),                      &sB[(hb) + d0]);           \
        async_cp16(Bst + (ko) + (size_t)128 * ldb,  &sB[(hb) + d0 + 4096]);    \
    } while (0)
#define RD_A4(hb, MO) do { _Pragma("unroll")                                   \
        for (int mi_ = 0; mi_ < 4; ++mi_)                                      \
            av[mi_] = *(const bf16x8*)&sA[(hb) + rdA + ((MO) + mi_) * 512];    \
    } while (0)
#define RD_B4(hb) do { _Pragma("unroll")                                       \
        for (int ni_ = 0; ni_ < 4; ++ni_)                                      \
            bv[ni_] = *(const bf16x8*)&sB[(hb) + rdB + ni_ * 512];             \
    } while (0)
#define SYNC_MFMA16(MO) do {                                                   \
        __builtin_amdgcn_s_barrier();                                          \
        asm volatile("s_waitcnt lgkmcnt(0)");                                  \
        __builtin_amdgcn_sched_barrier(0);                                     \
        __builtin_amdgcn_s_setprio(1);                                         \
        _Pragma("unroll")                                                      \
        for (int mi_ = 0; mi_ < 4; ++mi_)                                      \
            _Pragma("unroll")                                                  \
            for (int ni_ = 0; ni_ < 4; ++ni_)                                  \
                acc[(MO) + mi_][ni_] = __builtin_amdgcn_mfma_f32_16x16x32_bf16(\
                    av[mi_], bv[ni_], acc[(MO) + mi_][ni_], 0, 0, 0);          \
        __builtin_amdgcn_s_setprio(0);                                         \
    } while (0)

    // prologue: stage tile 0 fully (Ak0,Bk0,Ak1,Bk1); publish k-half 0
    STG_A(0, 0);      STG_B(0, 0);
    STG_A(8192, 32);  STG_B(8192, 32);
    asm volatile("s_waitcnt vmcnt(4)");
    __builtin_amdgcn_s_barrier();

#pragma unroll 1
    for (int t = 0; t < NT - 1; ++t) {
        const int cb = (t & 1) << 14;          // current buf base (0 / 16384)
        const int nb = cb ^ 16384;             // next buf base
        const size_t kt = (size_t)(t + 1) * 64;
        // ph0: kh0, mi 0-3 (+all B kh0); stage Ak0(t+1)
        RD_A4(cb, 0); RD_B4(cb);
        STG_A(nb, kt);
        SYNC_MFMA16(0);
        __builtin_amdgcn_s_barrier();
        // ph1: kh0, mi 4-7 (B reused); stage Bk0(t+1); publish kh1(t)
        RD_A4(cb, 4);
        STG_B(nb, kt);
        SYNC_MFMA16(4);
        asm volatile("s_waitcnt vmcnt(4)");
        __builtin_amdgcn_s_barrier();
        // ph2: kh1, mi 0-3 (+all B kh1); stage Ak1(t+1)
        RD_A4(cb + 8192, 0); RD_B4(cb + 8192);
        STG_A(nb + 8192, kt + 32);
        SYNC_MFMA16(0);
        __builtin_amdgcn_s_barrier();
        // ph3: kh1, mi 4-7; stage Bk1(t+1); publish kh0(t+1)
        RD_A4(cb + 8192, 4);
        STG_B(nb + 8192, kt + 32);
        SYNC_MFMA16(4);
        asm volatile("s_waitcnt vmcnt(4)");
        __builtin_amdgcn_s_barrier();
    }
    {   // peeled last tile: no staging, exact drains
        const int cb = ((NT - 1) & 1) << 14;
        RD_A4(cb, 0); RD_B4(cb);
        SYNC_MFMA16(0);
        __builtin_amdgcn_s_barrier();
        RD_A4(cb, 4);
        SYNC_MFMA16(4);
        asm volatile("s_waitcnt vmcnt(0)");    // publish kh1 of last tile
        __builtin_amdgcn_s_barrier();
        RD_A4(cb + 8192, 0); RD_B4(cb + 8192);
        SYNC_MFMA16(0);
        __builtin_amdgcn_s_barrier();
        RD_A4(cb + 8192, 4);
        SYNC_MFMA16(4);
    }
#undef SYNC_MFMA16
#undef RD_B4
#undef RD_A4
#undef STG_B
#undef STG_A

    // epilogue: D col = lane&15, row = quad*4 + reg
    if constexpr (F32OUT) {
        float* C = (float*)Cv + (size_t)z * ((size_t)M * N);
#pragma unroll
        for (int mi = 0; mi < 8; ++mi) {
            const int mr = m0 + wm * 128 + mi * 16 + quad * 4;
#pragma unroll
            for (int r = 0; r < 4; ++r) {
                float* Crow = C + (size_t)(mr + r) * N + n0 + wn * 64 + lr;
#pragma unroll
                for (int ni = 0; ni < 4; ++ni)
                    Crow[ni * 16] = acc[mi][ni][r];
            }
        }
    } else {
        u16* C = (u16*)Cv;
        float bvv[4];
#pragma unroll
        for (int ni = 0; ni < 4; ++ni)
            bvv[ni] = bias[n0 + wn * 64 + ni * 16 + lr];
#pragma unroll
        for (int mi = 0; mi < 8; ++mi) {
            const int mr = m0 + wm * 128 + mi * 16 + quad * 4;
#pragma unroll
            for (int r = 0; r < 4; ++r) {
                u16* Crow = C + (size_t)(mr + r) * N + n0 + wn * 64 + lr;
#pragma unroll
                for (int ni = 0; ni < 4; ++ni)
                    Crow[ni * 16] = f2b(acc[mi][ni][r] + bvv[ni]);
            }
        }
    }
}

// ---------- bf16 GEMM 128x128 (fallback for GEMM2 if ws too small) ----------
__global__ __launch_bounds__(256)
void gemm_bt_bias(const u16* __restrict__ A, const u16* __restrict__ Bt,
                  const float* __restrict__ bias, u16* __restrict__ C,
                  int M, int N, int K) {
    __shared__ __attribute__((aligned(16))) u16 sA[2][128 * 32];
    __shared__ __attribute__((aligned(16))) u16 sB[2][128 * 32];

    const int tid  = threadIdx.x;
    const int wid  = tid >> 6;
    const int lane = tid & 63;
    const int quad = lane >> 4;
    const int lr   = lane & 15;
    const int wm   = wid & 1;
    const int wn   = wid >> 1;

    const int NX = gridDim.x, NY = gridDim.y;
    const int bid = blockIdx.y * NX + blockIdx.x;
    const int xcd = bid & 7;
    const int j   = bid >> 3;
    const int yl  = j / NX;
    const int bx  = j - yl * NX;
    const int by  = xcd * (NY >> 3) + yl;

    const int m0 = by * 128;
    const int n0 = bx * 128;

    const int sr  = lane >> 2;
    const int scl = ((lane & 3) ^ ((lane >> 3) & 3)) * 8;
    const int qsw = (lr >> 1) & 3;

    const u16* Ag = A + (size_t)m0 * K;
    const u16* Bg = Bt + (size_t)n0 * K;

    f32x4 acc[4][4] = {};

    for (int k0 = 0; k0 < K; k0 += 64) {
#pragma unroll
        for (int s = 0; s < 2; ++s) {
#pragma unroll
            for (int i = 0; i < 2; ++i) {
                const int rb = wid * 32 + i * 16;
                async_cp16(Ag + (size_t)(rb + sr) * K + k0 + s * 32 + scl,
                           &sA[s][rb * 32]);
                async_cp16(Bg + (size_t)(rb + sr) * K + k0 + s * 32 + scl,
                           &sB[s][rb * 32]);
            }
        }
        __syncthreads();

#pragma unroll
        for (int s = 0; s < 2; ++s) {
            bf16x8 af[4], bfr[4];
#pragma unroll
            for (int mi = 0; mi < 4; ++mi)
                af[mi] = *(const bf16x8*)
                    &sA[s][(wm * 64 + mi * 16 + lr) * 32 + ((quad ^ qsw) * 8)];
#pragma unroll
            for (int ni = 0; ni < 4; ++ni)
                bfr[ni] = *(const bf16x8*)
                    &sB[s][(wn * 64 + ni * 16 + lr) * 32 + ((quad ^ qsw) * 8)];

#pragma unroll
            for (int mi = 0; mi < 4; ++mi)
#pragma unroll
                for (int ni = 0; ni < 4; ++ni)
                    acc[mi][ni] = __builtin_amdgcn_mfma_f32_16x16x32_bf16(
                        af[mi], bfr[ni], acc[mi][ni], 0, 0, 0);
        }

        __syncthreads();
    }

    float bvv[4];
#pragma unroll
    for (int ni = 0; ni < 4; ++ni)
        bvv[ni] = bias[n0 + wn * 64 + ni * 16 + lr];

#pragma unroll
    for (int mi = 0; mi < 4; ++mi) {
        const int mr = m0 + wm * 64 + mi * 16 + quad * 4;
#pragma unroll
        for (int r = 0; r < 4; ++r) {
            u16* Crow = C + (size_t)(mr + r) * N + n0 + wn * 64 + lr;
#pragma unroll
            for (int ni = 0; ni < 4; ++ni)
                Crow[ni * 16] = f2b(acc[mi][ni][r] + bvv[ni]);
        }
    }
}

// ---------- fused LN(4096) + GELU, in-place on bf16 h ----------
__global__ __launch_bounds__(256)
void ln_gelu_hid(u16* __restrict__ h, const float* __restrict__ g,
                 const float* __restrict__ be) {
    __shared__ float red[8];
    const int row = blockIdx.x;
    u16* hp = h + (size_t)row * HID_DIM;
    const int t = threadIdx.x;

    uint4 v0 = *(const uint4*)&hp[t * 8];
    uint4 v1 = *(const uint4*)&hp[(t + 256) * 8];

    float vals[16];
    {
        const uint32_t w0[4] = {v0.x, v0.y, v0.z, v0.w};
        const uint32_t w1[4] = {v1.x, v1.y, v1.z, v1.w};
#pragma unroll
        for (int q = 0; q < 4; ++q) {
            vals[q * 2]     = b2f((u16)(w0[q] & 0xffffu));
            vals[q * 2 + 1] = b2f((u16)(w0[q] >> 16));
            vals[8 + q * 2]     = b2f((u16)(w1[q] & 0xffffu));
            vals[8 + q * 2 + 1] = b2f((u16)(w1[q] >> 16));
        }
    }
    float s = 0.f, ss = 0.f;
#pragma unroll
    for (int i = 0; i < 16; ++i) { s += vals[i]; ss += vals[i] * vals[i]; }

    float4 gv[4], bv[4];
    gv[0] = *(const float4*)&g[t * 8];
    gv[1] = *(const float4*)&g[t * 8 + 4];
    gv[2] = *(const float4*)&g[(t + 256) * 8];
    gv[3] = *(const float4*)&g[(t + 256) * 8 + 4];
    bv[0] = *(const float4*)&be[t * 8];
    bv[1] = *(const float4*)&be[t * 8 + 4];
    bv[2] = *(const float4*)&be[(t + 256) * 8];
    bv[3] = *(const float4*)&be[(t + 256) * 8 + 4];

#pragma unroll
    for (int off = 32; off > 0; off >>= 1) {
        s += __shfl_down(s, off, 64);
        ss += __shfl_down(ss, off, 64);
    }
    if ((t & 63) == 0) { red[(t >> 6) * 2] = s; red[(t >> 6) * 2 + 1] = ss; }
    __syncthreads();
    s  = red[0] + red[2] + red[4] + red[6];
    ss = red[1] + red[3] + red[5] + red[7];
    const float mean = s * (1.f / HID_DIM);
    const float rstd = rsqrtf(ss * (1.f / HID_DIM) - mean * mean + 1e-5f);

    const float* gf = (const float*)gv;
    const float* bf = (const float*)bv;
#pragma unroll
    for (int j = 0; j < 2; ++j) {
        uint4 o;
        uint32_t* ow = (uint32_t*)&o;
#pragma unroll
        for (int q = 0; q < 4; ++q) {
            const int k = j * 8 + q * 2;
            float u0 = gelu_fast((vals[k]     - mean) * rstd * gf[k]     + bf[k]);
            float u1 = gelu_fast((vals[k + 1] - mean) * rstd * gf[k + 1] + bf[k + 1]);
            ow[q] = (uint32_t)f2b(u0) | ((uint32_t)f2b(u1) << 16);
        }
        *(uint4*)&hp[(t + j * 256) * 8] = o;
    }
}

// ---------- fused LN(1024) + GELU + weighted accumulate (bf16 y path) ----------
__global__ __launch_bounds__(256)
void ln_gelu_combine(const u16* __restrict__ y, const float* __restrict__ g,
                     const float* __restrict__ be, const float* __restrict__ wts,
                     float* __restrict__ out, int e, int first) {
    __shared__ float red[8];
    const int row = blockIdx.x;
    const u16* yp = y + (size_t)row * OUT_DIM;
    const int t = threadIdx.x;

    uint2 v = *(const uint2*)&yp[t * 4];
    float f0 = b2f((u16)(v.x & 0xffffu)), f1 = b2f((u16)(v.x >> 16));
    float f2 = b2f((u16)(v.y & 0xffffu)), f3 = b2f((u16)(v.y >> 16));
    float s = f0 + f1 + f2 + f3;
    float ss = f0 * f0 + f1 * f1 + f2 * f2 + f3 * f3;

    const int n = t * 4;
    float4 gv = *(const float4*)&g[n];
    float4 bvv = *(const float4*)&be[n];

#pragma unroll
    for (int off = 32; off > 0; off >>= 1) {
        s += __shfl_down(s, off, 64);
        ss += __shfl_down(ss, off, 64);
    }
    if ((t & 63) == 0) { red[(t >> 6) * 2] = s; red[(t >> 6) * 2 + 1] = ss; }
    __syncthreads();
    s  = red[0] + red[2] + red[4] + red[6];
    ss = red[1] + red[3] + red[5] + red[7];
    const float mean = s * (1.f / OUT_DIM);
    const float rstd = rsqrtf(ss * (1.f / OUT_DIM) - mean * mean + 1e-5f);

    const float w = wts[(size_t)row * NEXP + e];
    float4 o;
    if (first) { o.x = o.y = o.z = o.w = 0.f; }
    else       { o = *(const float4*)&out[(size_t)row * OUT_DIM + n]; }
    o.x += w * gelu_fast((f0 - mean) * rstd * gv.x + bvv.x);
    o.y += w * gelu_fast((f1 - mean) * rstd * gv.y + bvv.y);
    o.z += w * gelu_fast((f2 - mean) * rstd * gv.z + bvv.z);
    o.w += w * gelu_fast((f3 - mean) * rstd * gv.w + bvv.w);
    *(float4*)&out[(size_t)row * OUT_DIM + n] = o;
}

// ---------- split-K combine: y = p0+p1+b2, then LN + GELU + weighted acc ----------
__global__ __launch_bounds__(256)
void ln_gelu_combine_f32(const float* __restrict__ P, const float* __restrict__ g,
                         const float* __restrict__ be, const float* __restrict__ bs,
                         const float* __restrict__ wts, float* __restrict__ out,
                         int e, int first) {
    __shared__ float red[8];
    const int row = blockIdx.x;
    const int t = threadIdx.x;
    const int n = t * 4;

    const float* p0 = P + (size_t)row * OUT_DIM + n;
    const float* p1 = p0 + (size_t)B_DIM * OUT_DIM;
    float4 a  = *(const float4*)p0;
    float4 b  = *(const float4*)p1;
    float4 c  = *(const float4*)&bs[n];
    float f0 = a.x + b.x + c.x, f1 = a.y + b.y + c.y;
    float f2 = a.z + b.z + c.z, f3 = a.w + b.w + c.w;
    float s = f0 + f1 + f2 + f3;
    float ss = f0 * f0 + f1 * f1 + f2 * f2 + f3 * f3;

    float4 gv = *(const float4*)&g[n];
    float4 bvv = *(const float4*)&be[n];

#pragma unroll
    for (int off = 32; off > 0; off >>= 1) {
        s += __shfl_down(s, off, 64);
        ss += __shfl_down(ss, off, 64);
    }
    if ((t & 63) == 0) { red[(t >> 6) * 2] = s; red[(t >> 6) * 2 + 1] = ss; }
    __syncthreads();
    s  = red[0] + red[2] + red[4] + red[6];
    ss = red[1] + red[3] + red[5] + red[7];
    const float mean = s * (1.f / OUT_DIM);
    const float rstd = rsqrtf(ss * (1.f / OUT_DIM) - mean * mean + 1e-5f);

    const float w = wts[(size_t)row * NEXP + e];
    float4 o;
    if (first) { o.x = o.y = o.z = o.w = 0.f; }
    else       { o = *(const float4*)&out[(size_t)row * OUT_DIM + n]; }
    o.x += w * gelu_fast((f0 - mean) * rstd * gv.x + bvv.x);
    o.y += w * gelu_fast((f1 - mean) * rstd * gv.y + bvv.y);
    o.z += w * gelu_fast((f2 - mean) * rstd * gv.z + bvv.z);
    o.w += w * gelu_fast((f3 - mean) * rstd * gv.w + bvv.w);
    *(float4*)&out[(size_t)row * OUT_DIM + n] = o;
}

// ---------- launch ----------
extern "C" void kernel_launch(void* const* d_in, const int* in_sizes, int n_in,
                              void* d_out, int out_size, void* d_ws, size_t ws_size,
                              hipStream_t stream) {
    (void)in_sizes; (void)n_in; (void)out_size;
    const float* x   = (const float*)d_in[0];  // [8192,1024]
    const float* wts = (const float*)d_in[1];  // [8192,8]
    const float* W1  = (const float*)d_in[2];  // [8,1024,4096]
    const float* b1  = (const float*)d_in[3];  // [8,4096]
    const float* g1  = (const float*)d_in[4];  // [8,4096]
    const float* be1 = (const float*)d_in[5];  // [8,4096]
    const float* W2  = (const float*)d_in[6];  // [8,4096,1024]
    const float* b2  = (const float*)d_in[7];  // [8,1024]
    const float* g2  = (const float*)d_in[8];  // [8,1024]
    const float* be2 = (const float*)d_in[9];  // [8,1024]
    float* out = (float*)d_out;                // [8192,1024]

    // workspace carve: xb 16MB | w1t 8MB | w2t 8MB | h 64MB | P 64MB (or y 16MB)
    char* p = (char*)d_ws;
    u16* xb  = (u16*)p; p += (size_t)B_DIM * IN_DIM * 2;
    u16* w1t = (u16*)p; p += (size_t)HID_DIM * IN_DIM * 2;
    u16* w2t = (u16*)p; p += (size_t)OUT_DIM * HID_DIM * 2;
    u16* h   = (u16*)p; p += (size_t)B_DIM * HID_DIM * 2;
    float* P = (float*)p;                      // split path: 2 x 32MB fp32 partials
    u16*  y  = (u16*)p;                        // fallback path: 16MB bf16

    const size_t need = (size_t)B_DIM * IN_DIM * 2 + (size_t)HID_DIM * IN_DIM * 2 +
                        (size_t)OUT_DIM * HID_DIM * 2 + (size_t)B_DIM * HID_DIM * 2 +
                        (size_t)2 * B_DIM * OUT_DIM * 4;   // 160 MB
    const int splitk = (ws_size >= need) ? 1 : 0;

    cvt_bf16<<<(B_DIM * IN_DIM / 4 + 255) / 256, 256, 0, stream>>>(x, xb, B_DIM * IN_DIM / 4);

    for (int e = 0; e < NEXP; ++e) {
        transpose_cvt2<<<dim3(HID_DIM / 32, IN_DIM / 32, 2), 256, 0, stream>>>(
            W1 + (size_t)e * IN_DIM * HID_DIM, w1t,
            W2 + (size_t)e * HID_DIM * OUT_DIM, w2t);
        // h = xb @ W1[e] + b1[e]   (M=8192, N=4096, K=1024) — 8-phase 256^2
        gemm256_8ph<0><<<dim3(HID_DIM / 256, B_DIM / 256, 1), 512, 0, stream>>>(
            xb, w1t, b1 + (size_t)e * HID_DIM, h, B_DIM, HID_DIM, IN_DIM, IN_DIM, IN_DIM);
        // h = gelu(ln(h))
        ln_gelu_hid<<<B_DIM, 256, 0, stream>>>(h, g1 + (size_t)e * HID_DIM,
                                               be1 + (size_t)e * HID_DIM);
        if (splitk) {
            // P[s] = h @ W2[e] (K-slice s of 2048), fp32 partials; 256 blocks
            gemm256_8ph<1><<<dim3(OUT_DIM / 256, B_DIM / 256, 2), 512, 0, stream>>>(
                h, w2t, nullptr, P, B_DIM, OUT_DIM, HID_DIM, HID_DIM, HID_DIM / 2);
            // out (+)= wts[:,e] * gelu(ln(p0+p1+b2))
            ln_gelu_combine_f32<<<B_DIM, 256, 0, stream>>>(
                P, g2 + (size_t)e * OUT_DIM, be2 + (size_t)e * OUT_DIM,
                b2 + (size_t)e * OUT_DIM, wts, out, e, e == 0 ? 1 : 0);
        } else {
            // fallback: 128^2 GEMM2 + bf16 combine
            gemm_bt_bias<<<dim3(OUT_DIM / 128, B_DIM / 128), 256, 0, stream>>>(
                h, w2t, b2 + (size_t)e * OUT_DIM, y, B_DIM, OUT_DIM, HID_DIM);
            ln_gelu_combine<<<B_DIM, 256, 0, stream>>>(y, g2 + (size_t)e * OUT_DIM,
                                                       be2 + (size_t)e * OUT_DIM, wts, out,
                                                       e, e == 0 ? 1 : 0);
        }
    }
}